// Round 1
// baseline (512.871 us; speedup 1.0000x reference)
//
#include <hip/hip_runtime.h>
#include <stdint.h>

// Problem constants
#define S_LEN 2048
#define DIM_   4096
#define NH_    32
#define NKV_   8
#define HD_    128
#define QK_SCALE 0.08838834764831845f   // 1/sqrt(128)

typedef __attribute__((ext_vector_type(8))) short  s16x8;   // 8 bf16 (4 VGPRs) MFMA frag
typedef __attribute__((ext_vector_type(4))) float  f32x4;   // MFMA accum
typedef __attribute__((ext_vector_type(8))) unsigned short u16x8;
typedef __attribute__((ext_vector_type(4))) unsigned short u16x4;

__device__ __forceinline__ unsigned short f2bf(float f) {
  union { float f; uint32_t u; } v; v.f = f;
  return (unsigned short)((v.u + 0x7fffu + ((v.u >> 16) & 1u)) >> 16);   // RNE
}

// async global->LDS, 16B per lane. LDS dest is wave-uniform base + lane*16.
__device__ __forceinline__ void async_cp16(const void* g, void* l) {
  __builtin_amdgcn_global_load_lds(
      (const __attribute__((address_space(1))) unsigned int*)g,
      (__attribute__((address_space(3))) unsigned int*)l, 16, 0, 0);
}

// ---------------- cast fp32 -> bf16 (vectorized x4) ----------------
__global__ __launch_bounds__(256) void cast_f32_bf16(
    const float* __restrict__ src, unsigned short* __restrict__ dst, int n4) {
  const int i = blockIdx.x * 256 + threadIdx.x;
  if (i >= n4) return;
  const float4 v = ((const float4*)src)[i];
  u16x4 o; o[0] = f2bf(v.x); o[1] = f2bf(v.y); o[2] = f2bf(v.z); o[3] = f2bf(v.w);
  ((u16x4*)dst)[i] = o;
}

// ---------------- bf16 GEMM, C = A(MxK) * B^T(NxK), fp32 out -------
// m97 structure: 128x128 tile, BK=32, 4 waves (2x2), global_load_lds w=16.
__global__ __launch_bounds__(256) void gemm_bt(
    const unsigned short* __restrict__ A, const unsigned short* __restrict__ B,
    float* __restrict__ C, int M, int N, int K) {
  __shared__ unsigned short As[128 * 32];
  __shared__ unsigned short Bs[128 * 32];
  const int tid = threadIdx.x;
  const int wave = tid >> 6, lane = tid & 63;
  const int m0 = blockIdx.y * 128, n0 = blockIdx.x * 128;
  const int srow = lane >> 2, scol = (lane & 3) * 8;          // staging: 16 rows x 64B per 1KB chunk
  const int wr = (wave >> 1) * 64, wc = (wave & 1) * 64;
  const int fr = lane & 15, fk = (lane >> 4) * 8;

  f32x4 acc[4][4] = {};
  const unsigned short* Ab = A + (size_t)m0 * K;
  const unsigned short* Bb = B + (size_t)n0 * K;

  for (int k0 = 0; k0 < K; k0 += 32) {
#pragma unroll
    for (int i = 0; i < 2; ++i) {
      const int c = wave * 2 + i;
      const int row = c * 16 + srow;
      async_cp16(Ab + (size_t)row * K + k0 + scol, (char*)As + c * 1024);
      async_cp16(Bb + (size_t)row * K + k0 + scol, (char*)Bs + c * 1024);
    }
    __syncthreads();
    s16x8 a[4], b[4];
#pragma unroll
    for (int mi = 0; mi < 4; ++mi) a[mi] = *(const s16x8*)&As[(wr + mi * 16 + fr) * 32 + fk];
#pragma unroll
    for (int ni = 0; ni < 4; ++ni) b[ni] = *(const s16x8*)&Bs[(wc + ni * 16 + fr) * 32 + fk];
#pragma unroll
    for (int mi = 0; mi < 4; ++mi)
#pragma unroll
      for (int ni = 0; ni < 4; ++ni)
        acc[mi][ni] = __builtin_amdgcn_mfma_f32_16x16x32_bf16(a[mi], b[ni], acc[mi][ni], 0, 0, 0);
    __syncthreads();
  }
  const int or4 = (lane >> 4) * 4;
#pragma unroll
  for (int mi = 0; mi < 4; ++mi)
#pragma unroll
    for (int ni = 0; ni < 4; ++ni) {
      float* cp = C + (size_t)(m0 + wr + mi * 16 + or4) * N + (n0 + wc + ni * 16 + fr);
#pragma unroll
      for (int r = 0; r < 4; ++r) cp[(size_t)r * N] = acc[mi][ni][r];
    }
}

// ---------------- RoPE on Q (folds QK scale), fp32 -> bf16 ----------
__global__ __launch_bounds__(256) void rope_q_kern(
    const float* __restrict__ xqkv, const float* __restrict__ cos_f,
    const float* __restrict__ sin_f, unsigned short* __restrict__ qb) {
  const int gid = blockIdx.x * 256 + threadIdx.x;   // 2048*4096/8 items
  const int e0 = gid * 8;
  const int s = e0 >> 12;
  const int col = e0 & 4095;
  const int i0 = (col & 127) >> 1;                  // pair index, multiple of 4
  const float* src = xqkv + (size_t)s * 6144 + col;
  const float4 f1 = *(const float4*)src;
  const float4 f2 = *(const float4*)(src + 4);
  const float4 c  = *(const float4*)(cos_f + s * 64 + i0);
  const float4 sn = *(const float4*)(sin_f + s * 64 + i0);
  u16x8 o;
  o[0] = f2bf((f1.x * c.x - f1.y * sn.x) * QK_SCALE);
  o[1] = f2bf((f1.x * sn.x + f1.y * c.x) * QK_SCALE);
  o[2] = f2bf((f1.z * c.y - f1.w * sn.y) * QK_SCALE);
  o[3] = f2bf((f1.z * sn.y + f1.w * c.y) * QK_SCALE);
  o[4] = f2bf((f2.x * c.z - f2.y * sn.z) * QK_SCALE);
  o[5] = f2bf((f2.x * sn.z + f2.y * c.z) * QK_SCALE);
  o[6] = f2bf((f2.z * c.w - f2.w * sn.w) * QK_SCALE);
  o[7] = f2bf((f2.z * sn.w + f2.w * c.w) * QK_SCALE);
  *(u16x8*)(qb + e0) = o;
}

// ---------------- RoPE on K: fp32 cache out + bf16 attn K -----------
__global__ __launch_bounds__(256) void rope_k_kern(
    const float* __restrict__ xqkv, const float* __restrict__ cos_f,
    const float* __restrict__ sin_f, float* __restrict__ ck, unsigned short* __restrict__ kb) {
  const int gid = blockIdx.x * 256 + threadIdx.x;   // 2048*1024/8 items
  const int e0 = gid * 8;
  const int s = e0 >> 10;
  const int col = e0 & 1023;
  const int i0 = (col & 127) >> 1;
  const float* src = xqkv + (size_t)s * 6144 + 4096 + col;
  const float4 f1 = *(const float4*)src;
  const float4 f2 = *(const float4*)(src + 4);
  const float4 c  = *(const float4*)(cos_f + s * 64 + i0);
  const float4 sn = *(const float4*)(sin_f + s * 64 + i0);
  const float r0 = f1.x * c.x - f1.y * sn.x, r1 = f1.x * sn.x + f1.y * c.x;
  const float r2 = f1.z * c.y - f1.w * sn.y, r3 = f1.z * sn.y + f1.w * c.y;
  const float r4 = f2.x * c.z - f2.y * sn.z, r5 = f2.x * sn.z + f2.y * c.z;
  const float r6 = f2.z * c.w - f2.w * sn.w, r7 = f2.z * sn.w + f2.w * c.w;
  float4 o1; o1.x = r0; o1.y = r1; o1.z = r2; o1.w = r3;
  float4 o2; o2.x = r4; o2.y = r5; o2.z = r6; o2.w = r7;
  *(float4*)(ck + (size_t)s * 1024 + col) = o1;
  *(float4*)(ck + (size_t)s * 1024 + col + 4) = o2;
  u16x8 o;
  o[0] = f2bf(r0); o[1] = f2bf(r1); o[2] = f2bf(r2); o[3] = f2bf(r3);
  o[4] = f2bf(r4); o[5] = f2bf(r5); o[6] = f2bf(r6); o[7] = f2bf(r7);
  *(u16x8*)(kb + (size_t)s * 1024 + col) = o;
}

// ------- V: fp32 cache out (coalesced) + bf16 V^T [NKV*HD][S] -------
__global__ __launch_bounds__(256) void vtrans_kern(
    const float* __restrict__ xqkv, float* __restrict__ cv, unsigned short* __restrict__ vtb) {
  __shared__ float tile[64][65];
  const int st = blockIdx.x * 64;   // s tile
  const int ct = blockIdx.y * 64;   // col tile over 1024 (= kv*128+d)
  const int tid = threadIdx.x;
#pragma unroll
  for (int j = 0; j < 16; ++j) {
    const int lin = tid + j * 256;
    const int si = lin >> 6, ci = lin & 63;
    const float v = xqkv[(size_t)(st + si) * 6144 + 5120 + ct + ci];
    cv[(size_t)(st + si) * 1024 + ct + ci] = v;
    tile[si][ci] = v;
  }
  __syncthreads();
#pragma unroll
  for (int j = 0; j < 16; ++j) {
    const int lin = tid + j * 256;
    const int co = lin >> 6, so = lin & 63;
    vtb[(size_t)(ct + co) * 2048 + st + so] = f2bf(tile[so][co]);
  }
}

// ---------------- flash attention, causal, GQA ----------------------
// block = (qt, h): 64 q-rows of head h. 4 waves x 16 rows. KV tiles of 64.
// K LDS [64][128] and V^T LDS [128][64], XOR-swizzled (byte ^= (row&7)<<4)
// via pre-swizzled global source (global_load_lds writes linearly).
__global__ __launch_bounds__(256) void attn_fwd(
    const unsigned short* __restrict__ qb, const unsigned short* __restrict__ kb,
    const unsigned short* __restrict__ vtb, unsigned short* __restrict__ ob) {
  __shared__ unsigned short Ks[64 * 128];
  __shared__ unsigned short Vs[128 * 64];
  __shared__ unsigned short Ps[4 * 16 * 64];
  const int qt = blockIdx.x, h = blockIdx.y;
  const int hkv = h >> 2;
  const int tid = threadIdx.x, wave = tid >> 6, lane = tid & 63;
  const int fr = lane & 15, fhi = lane >> 4, fk = fhi * 8;
  const int q0 = qt * 64;
  const int qrow = q0 + wave * 16;

  // Q fragments direct global->reg, constant over the KV loop (scale pre-folded)
  s16x8 aq[4];
#pragma unroll
  for (int ks = 0; ks < 4; ++ks)
    aq[ks] = *(const s16x8*)&qb[(size_t)(qrow + fr) * 4096 + h * 128 + ks * 32 + fk];

  f32x4 oacc[8] = {};
  float m_r[4], l_r[4];
#pragma unroll
  for (int r = 0; r < 4; ++r) { m_r[r] = -3e30f; l_r[r] = 0.0f; }

  unsigned short* Pw = Ps + wave * (16 * 64);

  for (int kt = 0; kt <= qt; ++kt) {
    const int kv0 = kt * 64;
    // stage K tile: chunk c = 4 rows of 256B; lane -> row 4c+(lane>>4), 16B slot (lane&15)
#pragma unroll
    for (int i = 0; i < 4; ++i) {
      const int c = wave * 4 + i;
      const int row = c * 4 + fhi;
      const int cb = ((lane & 15) * 16) ^ ((row & 7) << 4);    // pre-swizzled source col-bytes
      async_cp16(kb + (size_t)(kv0 + row) * 1024 + hkv * 128 + (cb >> 1), (char*)Ks + c * 1024);
    }
    // stage V^T tile: chunk c = 8 rows of 128B; lane -> row 8c+(lane>>3), slot (lane&7)
#pragma unroll
    for (int i = 0; i < 4; ++i) {
      const int c = wave * 4 + i;
      const int row = c * 8 + (lane >> 3);
      const int cb = ((lane & 7) * 16) ^ ((row & 7) << 4);
      async_cp16(vtb + (size_t)hkv * HD_ * S_LEN + (size_t)row * S_LEN + kv0 + (cb >> 1),
                 (char*)Vs + c * 1024);
    }
    __syncthreads();

    // S = Q K^T  (16x64 per wave)
    f32x4 sacc[4] = {};
#pragma unroll
    for (int ks = 0; ks < 4; ++ks)
#pragma unroll
      for (int ni = 0; ni < 4; ++ni) {
        const int row = ni * 16 + fr;
        const int cb = ((ks * 32 + fk) * 2) ^ ((row & 7) << 4);
        const s16x8 bk = *(const s16x8*)((const char*)Ks + row * 256 + cb);
        sacc[ni] = __builtin_amdgcn_mfma_f32_16x16x32_bf16(aq[ks], bk, sacc[ni], 0, 0, 0);
      }

    // causal mask on the diagonal tile
    if (kt == qt) {
#pragma unroll
      for (int ni = 0; ni < 4; ++ni) {
        const int kg = kv0 + ni * 16 + fr;
#pragma unroll
        for (int r = 0; r < 4; ++r) {
          const int qg = qrow + fhi * 4 + r;
          if (kg > qg) sacc[ni][r] = -3e30f;
        }
      }
    }

    // online softmax (rows live on reg index; cols across 16-lane group + 4 frags)
    float p[4][4], scl[4];
#pragma unroll
    for (int r = 0; r < 4; ++r) {
      float mx = fmaxf(fmaxf(sacc[0][r], sacc[1][r]), fmaxf(sacc[2][r], sacc[3][r]));
#pragma unroll
      for (int off = 1; off < 16; off <<= 1) mx = fmaxf(mx, __shfl_xor(mx, off));
      const float mn = fmaxf(m_r[r], mx);
      scl[r] = __expf(m_r[r] - mn);
      float sum = 0.f;
#pragma unroll
      for (int ni = 0; ni < 4; ++ni) { const float e = __expf(sacc[ni][r] - mn); p[ni][r] = e; sum += e; }
#pragma unroll
      for (int off = 1; off < 16; off <<= 1) sum += __shfl_xor(sum, off);
      l_r[r] = l_r[r] * scl[r] + sum;
      m_r[r] = mn;
    }
#pragma unroll
    for (int ni = 0; ni < 8; ++ni)
#pragma unroll
      for (int r = 0; r < 4; ++r) oacc[ni][r] *= scl[r];

    // P -> wave-private LDS (swizzled), then PV
#pragma unroll
    for (int ni = 0; ni < 4; ++ni)
#pragma unroll
      for (int r = 0; r < 4; ++r) {
        const int prow = fhi * 4 + r;
        const int pcb = ((ni * 16 + fr) * 2) ^ ((prow & 7) << 4);
        *(unsigned short*)((char*)Pw + prow * 128 + pcb) = f2bf(p[ni][r]);
      }
#pragma unroll
    for (int ks2 = 0; ks2 < 2; ++ks2) {
      const int pcb = ((ks2 * 32 + fk) * 2) ^ ((fr & 7) << 4);
      const s16x8 ap = *(const s16x8*)((const char*)Pw + fr * 128 + pcb);
#pragma unroll
      for (int ni = 0; ni < 8; ++ni) {
        const int vrow = ni * 16 + fr;
        const int vcb = ((ks2 * 32 + fk) * 2) ^ ((vrow & 7) << 4);
        const s16x8 bv = *(const s16x8*)((const char*)Vs + vrow * 128 + vcb);
        oacc[ni] = __builtin_amdgcn_mfma_f32_16x16x32_bf16(ap, bv, oacc[ni], 0, 0, 0);
      }
    }
    __syncthreads();
  }

  // normalize + write O (bf16, [S][NH*HD])
#pragma unroll
  for (int r = 0; r < 4; ++r) l_r[r] = 1.0f / l_r[r];
#pragma unroll
  for (int ni = 0; ni < 8; ++ni)
#pragma unroll
    for (int r = 0; r < 4; ++r) {
      const int rq = qrow + fhi * 4 + r;
      ob[(size_t)rq * 4096 + h * 128 + ni * 16 + fr] = f2bf(oacc[ni][r] * l_r[r]);
    }
}

// ------------------------------ launch ------------------------------
extern "C" void kernel_launch(void* const* d_in, const int* in_sizes, int n_in,
                              void* d_out, int out_size, void* d_ws, size_t ws_size,
                              hipStream_t stream) {
  const float* x     = (const float*)d_in[0];
  const float* cos_f = (const float*)d_in[1];
  const float* sin_f = (const float*)d_in[2];
  // d_in[3] = mask (pure causal here, unused), d_in[8..10] = zero caches / positions (unused)
  const float* wq = (const float*)d_in[4];
  const float* wk = (const float*)d_in[5];
  const float* wv = (const float*)d_in[6];
  const float* wo = (const float*)d_in[7];
  float* out = (float*)d_out;

  // workspace layout (bytes); total 192,937,984
  char* ws = (char*)d_ws;
  unsigned short* xb    = (unsigned short*)(ws);                 // 2048x4096 bf16
  unsigned short* wqkvb = (unsigned short*)(ws + 16777216);      // 6144x4096 bf16 (wq|wk|wv)
  unsigned short* wob   = (unsigned short*)(ws + 67108864);      // 4096x4096 bf16
  float*          xqkv  = (float*)(ws + 100663296);              // 2048x6144 fp32
  unsigned short* qb    = (unsigned short*)(ws + 150994944);     // 2048x4096 bf16 (roped*scale)
  unsigned short* kb    = (unsigned short*)(ws + 167772160);     // 2048x1024 bf16 (roped)
  unsigned short* vtb   = (unsigned short*)(ws + 171966464);     // [8*128][2048] bf16 (V^T)
  unsigned short* attno = (unsigned short*)(ws + 176160768);     // 2048x4096 bf16

  // casts
  cast_f32_bf16<<<dim3(8192), 256, 0, stream>>>(x, xb, 2097152);
  cast_f32_bf16<<<dim3(16384), 256, 0, stream>>>(wq, wqkvb, 4194304);
  cast_f32_bf16<<<dim3(4096), 256, 0, stream>>>(wk, wqkvb + 16777216, 1048576);
  cast_f32_bf16<<<dim3(4096), 256, 0, stream>>>(wv, wqkvb + 20971520, 1048576);
  cast_f32_bf16<<<dim3(16384), 256, 0, stream>>>(wo, wob, 4194304);

  // fused QKV projection: [2048x4096] x [6144x4096]^T -> [2048x6144] fp32
  gemm_bt<<<dim3(48, 16), 256, 0, stream>>>(xb, wqkvb, xqkv, 2048, 6144, 4096);

  // RoPE + cache writes + attn-layout conversions
  rope_q_kern<<<dim3(4096), 256, 0, stream>>>(xqkv, cos_f, sin_f, qb);
  rope_k_kern<<<dim3(1024), 256, 0, stream>>>(xqkv, cos_f, sin_f, out + 8388608, kb);
  vtrans_kern<<<dim3(32, 16), 256, 0, stream>>>(xqkv, out + 12582912, vtb);

  // zero cache tails (rows 2048..4095 of each cache)
  (void)hipMemsetAsync(out + 10485760, 0, 8388608, stream);
  (void)hipMemsetAsync(out + 14680064, 0, 8388608, stream);

  // attention
  attn_fwd<<<dim3(32, 32), 256, 0, stream>>>(qb, kb, vtb, attno);

  // output projection: [2048x4096] x [4096x4096]^T -> d_out fp32
  gemm_bt<<<dim3(32, 16), 256, 0, stream>>>(attno, wob, out, 2048, 4096, 4096);
}

// Round 2
// 402.679 us; speedup vs baseline: 1.2736x; 1.2736x over previous
//
#include <hip/hip_runtime.h>
#include <stdint.h>

// Problem constants
#define S_LEN 2048
#define DIM_   4096
#define NH_    32
#define NKV_   8
#define HD_    128
#define QK_SCALE 0.08838834764831845f   // 1/sqrt(128)

typedef __attribute__((ext_vector_type(8)))  short  s16x8;   // 8 bf16 (4 VGPRs) MFMA frag
typedef __attribute__((ext_vector_type(4)))  float  f32x4;   // 16x16 MFMA accum
typedef __attribute__((ext_vector_type(16))) float  f32x16;  // 32x32 MFMA accum
typedef __attribute__((ext_vector_type(8))) unsigned short u16x8;
typedef __attribute__((ext_vector_type(4))) unsigned short u16x4;

union frag_u { s16x8 f; uint32_t w[4]; };

__device__ __forceinline__ unsigned short f2bf(float f) {
  union { float f; uint32_t u; } v; v.f = f;
  return (unsigned short)((v.u + 0x7fffu + ((v.u >> 16) & 1u)) >> 16);   // RNE
}

__device__ __forceinline__ uint32_t cvt_pk_bf16(float lo, float hi2) {
  uint32_t r;
  asm volatile("v_cvt_pk_bf16_f32 %0, %1, %2" : "=v"(r) : "v"(lo), "v"(hi2));
  return r;
}

// async global->LDS, 16B per lane. LDS dest is wave-uniform base + lane*16.
__device__ __forceinline__ void async_cp16(const void* g, void* l) {
  __builtin_amdgcn_global_load_lds(
      (const __attribute__((address_space(1))) unsigned int*)g,
      (__attribute__((address_space(3))) unsigned int*)l, 16, 0, 0);
}

// ---------------- cast fp32 -> bf16 (vectorized x4) ----------------
__global__ __launch_bounds__(256) void cast_f32_bf16(
    const float* __restrict__ src, unsigned short* __restrict__ dst, int n4) {
  const int i = blockIdx.x * 256 + threadIdx.x;
  if (i >= n4) return;
  const float4 v = ((const float4*)src)[i];
  u16x4 o; o[0] = f2bf(v.x); o[1] = f2bf(v.y); o[2] = f2bf(v.z); o[3] = f2bf(v.w);
  ((u16x4*)dst)[i] = o;
}

// ---------------- bf16 GEMM, C = A(MxK) * B^T(NxK), fp32 out -------
__global__ __launch_bounds__(256) void gemm_bt(
    const unsigned short* __restrict__ A, const unsigned short* __restrict__ B,
    float* __restrict__ C, int M, int N, int K) {
  __shared__ unsigned short As[128 * 32];
  __shared__ unsigned short Bs[128 * 32];
  const int tid = threadIdx.x;
  const int wave = tid >> 6, lane = tid & 63;
  const int m0 = blockIdx.y * 128, n0 = blockIdx.x * 128;
  const int srow = lane >> 2, scol = (lane & 3) * 8;
  const int wr = (wave >> 1) * 64, wc = (wave & 1) * 64;
  const int fr = lane & 15, fk = (lane >> 4) * 8;

  f32x4 acc[4][4] = {};
  const unsigned short* Ab = A + (size_t)m0 * K;
  const unsigned short* Bb = B + (size_t)n0 * K;

  for (int k0 = 0; k0 < K; k0 += 32) {
#pragma unroll
    for (int i = 0; i < 2; ++i) {
      const int c = wave * 2 + i;
      const int row = c * 16 + srow;
      async_cp16(Ab + (size_t)row * K + k0 + scol, (char*)As + c * 1024);
      async_cp16(Bb + (size_t)row * K + k0 + scol, (char*)Bs + c * 1024);
    }
    __syncthreads();
    s16x8 a[4], b[4];
#pragma unroll
    for (int mi = 0; mi < 4; ++mi) a[mi] = *(const s16x8*)&As[(wr + mi * 16 + fr) * 32 + fk];
#pragma unroll
    for (int ni = 0; ni < 4; ++ni) b[ni] = *(const s16x8*)&Bs[(wc + ni * 16 + fr) * 32 + fk];
#pragma unroll
    for (int mi = 0; mi < 4; ++mi)
#pragma unroll
      for (int ni = 0; ni < 4; ++ni)
        acc[mi][ni] = __builtin_amdgcn_mfma_f32_16x16x32_bf16(a[mi], b[ni], acc[mi][ni], 0, 0, 0);
    __syncthreads();
  }
  const int or4 = (lane >> 4) * 4;
#pragma unroll
  for (int mi = 0; mi < 4; ++mi)
#pragma unroll
    for (int ni = 0; ni < 4; ++ni) {
      float* cp = C + (size_t)(m0 + wr + mi * 16 + or4) * N + (n0 + wc + ni * 16 + fr);
#pragma unroll
      for (int r = 0; r < 4; ++r) cp[(size_t)r * N] = acc[mi][ni][r];
    }
}

// ---------------- RoPE on Q (folds QK scale), fp32 -> bf16 ----------
__global__ __launch_bounds__(256) void rope_q_kern(
    const float* __restrict__ xqkv, const float* __restrict__ cos_f,
    const float* __restrict__ sin_f, unsigned short* __restrict__ qb) {
  const int gid = blockIdx.x * 256 + threadIdx.x;
  const int e0 = gid * 8;
  const int s = e0 >> 12;
  const int col = e0 & 4095;
  const int i0 = (col & 127) >> 1;
  const float* src = xqkv + (size_t)s * 6144 + col;
  const float4 f1 = *(const float4*)src;
  const float4 f2 = *(const float4*)(src + 4);
  const float4 c  = *(const float4*)(cos_f + s * 64 + i0);
  const float4 sn = *(const float4*)(sin_f + s * 64 + i0);
  u16x8 o;
  o[0] = f2bf((f1.x * c.x - f1.y * sn.x) * QK_SCALE);
  o[1] = f2bf((f1.x * sn.x + f1.y * c.x) * QK_SCALE);
  o[2] = f2bf((f1.z * c.y - f1.w * sn.y) * QK_SCALE);
  o[3] = f2bf((f1.z * sn.y + f1.w * c.y) * QK_SCALE);
  o[4] = f2bf((f2.x * c.z - f2.y * sn.z) * QK_SCALE);
  o[5] = f2bf((f2.x * sn.z + f2.y * c.z) * QK_SCALE);
  o[6] = f2bf((f2.z * c.w - f2.w * sn.w) * QK_SCALE);
  o[7] = f2bf((f2.z * sn.w + f2.w * c.w) * QK_SCALE);
  *(u16x8*)(qb + e0) = o;
}

// ---------------- RoPE on K: fp32 cache out + bf16 attn K -----------
__global__ __launch_bounds__(256) void rope_k_kern(
    const float* __restrict__ xqkv, const float* __restrict__ cos_f,
    const float* __restrict__ sin_f, float* __restrict__ ck, unsigned short* __restrict__ kb) {
  const int gid = blockIdx.x * 256 + threadIdx.x;
  const int e0 = gid * 8;
  const int s = e0 >> 10;
  const int col = e0 & 1023;
  const int i0 = (col & 127) >> 1;
  const float* src = xqkv + (size_t)s * 6144 + 4096 + col;
  const float4 f1 = *(const float4*)src;
  const float4 f2 = *(const float4*)(src + 4);
  const float4 c  = *(const float4*)(cos_f + s * 64 + i0);
  const float4 sn = *(const float4*)(sin_f + s * 64 + i0);
  const float r0 = f1.x * c.x - f1.y * sn.x, r1 = f1.x * sn.x + f1.y * c.x;
  const float r2 = f1.z * c.y - f1.w * sn.y, r3 = f1.z * sn.y + f1.w * c.y;
  const float r4 = f2.x * c.z - f2.y * sn.z, r5 = f2.x * sn.z + f2.y * c.z;
  const float r6 = f2.z * c.w - f2.w * sn.w, r7 = f2.z * sn.w + f2.w * c.w;
  float4 o1; o1.x = r0; o1.y = r1; o1.z = r2; o1.w = r3;
  float4 o2; o2.x = r4; o2.y = r5; o2.z = r6; o2.w = r7;
  *(float4*)(ck + (size_t)s * 1024 + col) = o1;
  *(float4*)(ck + (size_t)s * 1024 + col + 4) = o2;
  u16x8 o;
  o[0] = f2bf(r0); o[1] = f2bf(r1); o[2] = f2bf(r2); o[3] = f2bf(r3);
  o[4] = f2bf(r4); o[5] = f2bf(r5); o[6] = f2bf(r6); o[7] = f2bf(r7);
  *(u16x8*)(kb + (size_t)s * 1024 + col) = o;
}

// ------- V: fp32 cache out (coalesced) + bf16 V^T [NKV*HD][S] -------
__global__ __launch_bounds__(256) void vtrans_kern(
    const float* __restrict__ xqkv, float* __restrict__ cv, unsigned short* __restrict__ vtb) {
  __shared__ float tile[64][65];
  const int st = blockIdx.x * 64;
  const int ct = blockIdx.y * 64;
  const int tid = threadIdx.x;
#pragma unroll
  for (int j = 0; j < 16; ++j) {
    const int lin = tid + j * 256;
    const int si = lin >> 6, ci = lin & 63;
    const float v = xqkv[(size_t)(st + si) * 6144 + 5120 + ct + ci];
    cv[(size_t)(st + si) * 1024 + ct + ci] = v;
    tile[si][ci] = v;
  }
  __syncthreads();
#pragma unroll
  for (int j = 0; j < 16; ++j) {
    const int lin = tid + j * 256;
    const int co = lin >> 6, so = lin & 63;
    vtb[(size_t)(ct + co) * 2048 + st + so] = f2bf(tile[so][co]);
  }
}

// ---------------- flash attention v2: swapped-QK, in-reg softmax ----
// block = 128 q-rows x head. 4 waves x 32 q-rows (32x32x16 MFMA).
// KV tiles of 64, K/V^T double-buffered in LDS (XOR-swizzled), 1 barrier/tile.
// S^T = mfma(K,Q): lane holds S[q=lane&31][16 kv on regs]; partner lane (^32)
// holds the complementary 16 of 32 per kv-block. Softmax fully in-register.
__global__ __launch_bounds__(256, 2) void attn_fwd2(
    const unsigned short* __restrict__ qb, const unsigned short* __restrict__ kb,
    const unsigned short* __restrict__ vtb, unsigned short* __restrict__ ob) {
  __shared__ unsigned short Ks[2][64 * 128];   // 32 KB
  __shared__ unsigned short Vs[2][128 * 64];   // 32 KB  (total 64 KB exactly)
  const int bx = blockIdx.x;            // 0..15 slot
  const int h  = blockIdx.y;            // 0..31
  const int hkv = h >> 2;
  // balanced causal schedule: g = [0,15,1,14,...]; reflect across head halves
  const int g = (bx & 1) ? (15 - (bx >> 1)) : (bx >> 1);
  const int qtile = (h < 16) ? g : (15 - g);
  const int q0 = qtile * 128;
  const int tid = threadIdx.x, wave = tid >> 6, lane = tid & 63;
  const int col = lane & 31;
  const int hi  = lane >> 5;
  const int q0w = q0 + wave * 32;
  const int nt = (q0 >> 6) + 2;

  // Q B-frags (held all loop): lane holds Q[q0w+col][16ks+8hi .. +8)
  s16x8 qf[8];
  {
    const unsigned short* qrow = qb + (size_t)(q0w + col) * 4096 + h * 128 + hi * 8;
#pragma unroll
    for (int ks = 0; ks < 8; ++ks) qf[ks] = *(const s16x8*)(qrow + ks * 16);
  }

  f32x16 oacc[4] = {};
  float m_s = -3e30f, l_s = 0.0f;

  // staging (same swizzle scheme as r1 kernel, verified)
#define STAGE_K(KT, B)                                                        \
  {                                                                           \
    const unsigned short* src = kb + (size_t)((KT) * 64) * 1024 + hkv * 128;  \
    _Pragma("unroll")                                                         \
    for (int i_ = 0; i_ < 4; ++i_) {                                          \
      const int c_ = wave * 4 + i_;                                           \
      const int row_ = c_ * 4 + (lane >> 4);                                  \
      const int cb_ = ((lane & 15) * 16) ^ ((row_ & 7) << 4);                 \
      async_cp16(src + (size_t)row_ * 1024 + (cb_ >> 1), (char*)Ks[B] + c_ * 1024); \
    }                                                                         \
  }
#define STAGE_V(KT, B)                                                        \
  {                                                                           \
    const unsigned short* src = vtb + (size_t)hkv * (128 * 2048) + (KT) * 64; \
    _Pragma("unroll")                                                         \
    for (int i_ = 0; i_ < 4; ++i_) {                                          \
      const int c_ = wave * 4 + i_;                                           \
      const int row_ = c_ * 8 + (lane >> 3);                                  \
      const int cb_ = ((lane & 7) * 16) ^ ((row_ & 7) << 4);                  \
      async_cp16(src + (size_t)row_ * 2048 + (cb_ >> 1), (char*)Vs[B] + c_ * 1024); \
    }                                                                         \
  }

  STAGE_K(0, 0); STAGE_V(0, 0);
  __syncthreads();

  for (int kt = 0; kt < nt; ++kt) {
    const int kv0 = kt * 64;
    const int cur = kt & 1;
    if (kt + 1 < nt) { STAGE_K(kt + 1, cur ^ 1); STAGE_V(kt + 1, cur ^ 1); }

    if (kv0 < q0w + 32) {
      // ---- S^T = K * Q^T : two 32x32 kv-blocks ----
      f32x16 s0 = {}, s1 = {};
#pragma unroll
      for (int ks = 0; ks < 8; ++ks) {
        const int gcb = 32 * ks + 16 * hi;
        const int sw = (col & 7) << 4;                  // (row&7)<<4, same for both blocks
        const s16x8 k0 = *(const s16x8*)((const char*)Ks[cur] + col * 256 + (gcb ^ sw));
        const s16x8 k1 = *(const s16x8*)((const char*)Ks[cur] + (32 + col) * 256 + (gcb ^ sw));
        s0 = __builtin_amdgcn_mfma_f32_32x32x16_bf16(k0, qf[ks], s0, 0, 0, 0);
        s1 = __builtin_amdgcn_mfma_f32_32x32x16_bf16(k1, qf[ks], s1, 0, 0, 0);
      }

      const int qg = q0w + col;
      if (kv0 + 63 > q0w) {                             // diagonal tile: causal mask
#pragma unroll
        for (int r = 0; r < 16; ++r) {
          const int kvl = (r & 3) + 8 * (r >> 2) + 4 * hi;
          if (kv0 + kvl > qg)      s0[r] = -3e30f;
          if (kv0 + 32 + kvl > qg) s1[r] = -3e30f;
        }
      }

      // ---- online softmax, fully in-register (q = lane&31) ----
      float mxl = s0[0];
#pragma unroll
      for (int r = 1; r < 16; ++r) mxl = fmaxf(mxl, s0[r]);
#pragma unroll
      for (int r = 0; r < 16; ++r) mxl = fmaxf(mxl, s1[r]);
      const float mxf = fmaxf(mxl, __shfl_xor(mxl, 32));
      if (__any(mxf > m_s + 8.0f)) {                    // defer-max (T13)
        const float mn = fmaxf(m_s, mxf);
        const float scl = __expf(m_s - mn);
        m_s = mn;
        l_s *= scl;
#pragma unroll
        for (int r = 0; r < 16; ++r) {                  // col->reg broadcast of scl
          const int qq = (r & 3) + 8 * (r >> 2) + 4 * hi;
          const float sr = __int_as_float(
              __builtin_amdgcn_ds_bpermute(qq * 4, __float_as_int(scl)));
          oacc[0][r] *= sr; oacc[1][r] *= sr; oacc[2][r] *= sr; oacc[3][r] *= sr;
        }
      }
      float lsum = 0.0f;
#pragma unroll
      for (int r = 0; r < 16; ++r) {
        s0[r] = __expf(s0[r] - m_s); s1[r] = __expf(s1[r] - m_s);
        lsum += s0[r] + s1[r];
      }
      lsum += __shfl_xor(lsum, 32);
      l_s += lsum;

      // ---- P -> A-frags (cvt_pk + one shfl per word pair) + PV ----
#define PV_STEP(KS, PP)                                                       \
      {                                                                       \
        const int rb2 = 8 * ((KS) & 1);                                       \
        const uint32_t g0a = cvt_pk_bf16(PP[rb2 + 0], PP[rb2 + 1]);           \
        const uint32_t g0b = cvt_pk_bf16(PP[rb2 + 2], PP[rb2 + 3]);           \
        const uint32_t g1a = cvt_pk_bf16(PP[rb2 + 4], PP[rb2 + 5]);           \
        const uint32_t g1b = cvt_pk_bf16(PP[rb2 + 6], PP[rb2 + 7]);           \
        const uint32_t sa = hi ? g0a : g1a, sb = hi ? g0b : g1b;              \
        const uint32_t ra = (uint32_t)__shfl_xor((int)sa, 32);                \
        const uint32_t rb_ = (uint32_t)__shfl_xor((int)sb, 32);               \
        frag_u af;                                                            \
        af.w[0] = hi ? ra  : g0a; af.w[1] = hi ? rb_ : g0b;                   \
        af.w[2] = hi ? g1a : ra;  af.w[3] = hi ? g1b : rb_;                   \
        const int gcb = 32 * (KS) + 16 * hi;                                  \
        const int vsw = (col & 7) << 4;                                       \
        _Pragma("unroll")                                                     \
        for (int db = 0; db < 4; ++db) {                                      \
          const s16x8 bv = *(const s16x8*)((const char*)Vs[cur] +             \
              (db * 32 + col) * 128 + (gcb ^ vsw));                           \
          oacc[db] = __builtin_amdgcn_mfma_f32_32x32x16_bf16(af.f, bv, oacc[db], 0, 0, 0); \
        }                                                                     \
      }
      PV_STEP(0, s0); PV_STEP(1, s0); PV_STEP(2, s1); PV_STEP(3, s1);
#undef PV_STEP
    }
    __syncthreads();   // drains next-tile staging + protects LDS reuse
  }

  // ---- epilogue: broadcast 1/l (col->reg), normalize, store ----
  const float linv = 1.0f / l_s;
#pragma unroll
  for (int r = 0; r < 16; ++r) {
    const int qq = (r & 3) + 8 * (r >> 2) + 4 * hi;
    const float lr = __int_as_float(
        __builtin_amdgcn_ds_bpermute(qq * 4, __float_as_int(linv)));
    unsigned short* orow = ob + (size_t)(q0w + qq) * 4096 + h * 128 + col;
#pragma unroll
    for (int db = 0; db < 4; ++db)
      orow[db * 32] = f2bf(oacc[db][r] * lr);
  }
#undef STAGE_K
#undef STAGE_V
}

// ------------------------------ launch ------------------------------
extern "C" void kernel_launch(void* const* d_in, const int* in_sizes, int n_in,
                              void* d_out, int out_size, void* d_ws, size_t ws_size,
                              hipStream_t stream) {
  const float* x     = (const float*)d_in[0];
  const float* cos_f = (const float*)d_in[1];
  const float* sin_f = (const float*)d_in[2];
  const float* wq = (const float*)d_in[4];
  const float* wk = (const float*)d_in[5];
  const float* wv = (const float*)d_in[6];
  const float* wo = (const float*)d_in[7];
  float* out = (float*)d_out;

  char* ws = (char*)d_ws;
  unsigned short* xb    = (unsigned short*)(ws);                 // 2048x4096 bf16
  unsigned short* wqkvb = (unsigned short*)(ws + 16777216);      // 6144x4096 bf16
  unsigned short* wob   = (unsigned short*)(ws + 67108864);      // 4096x4096 bf16
  float*          xqkv  = (float*)(ws + 100663296);              // 2048x6144 fp32
  unsigned short* qb    = (unsigned short*)(ws + 150994944);     // 2048x4096 bf16
  unsigned short* kb    = (unsigned short*)(ws + 167772160);     // 2048x1024 bf16
  unsigned short* vtb   = (unsigned short*)(ws + 171966464);     // [8*128][2048] bf16
  unsigned short* attno = (unsigned short*)(ws + 176160768);     // 2048x4096 bf16

  cast_f32_bf16<<<dim3(8192), 256, 0, stream>>>(x, xb, 2097152);
  cast_f32_bf16<<<dim3(16384), 256, 0, stream>>>(wq, wqkvb, 4194304);
  cast_f32_bf16<<<dim3(4096), 256, 0, stream>>>(wk, wqkvb + 16777216, 1048576);
  cast_f32_bf16<<<dim3(4096), 256, 0, stream>>>(wv, wqkvb + 20971520, 1048576);
  cast_f32_bf16<<<dim3(16384), 256, 0, stream>>>(wo, wob, 4194304);

  gemm_bt<<<dim3(48, 16), 256, 0, stream>>>(xb, wqkvb, xqkv, 2048, 6144, 4096);

  rope_q_kern<<<dim3(4096), 256, 0, stream>>>(xqkv, cos_f, sin_f, qb);
  rope_k_kern<<<dim3(1024), 256, 0, stream>>>(xqkv, cos_f, sin_f, out + 8388608, kb);
  vtrans_kern<<<dim3(32, 16), 256, 0, stream>>>(xqkv, out + 12582912, vtb);

  (void)hipMemsetAsync(out + 10485760, 0, 8388608, stream);
  (void)hipMemsetAsync(out + 14680064, 0, 8388608, stream);

  attn_fwd2<<<dim3(16, 32), 256, 0, stream>>>(qb, kb, vtb, attno);

  gemm_bt<<<dim3(32, 16), 256, 0, stream>>>(attno, wob, out, 2048, 4096, 4096);
}